// Round 5
// baseline (11427.856 us; speedup 1.0000x reference)
//
#include <hip/hip_runtime.h>
#include <cstdint>

#define NBATCH 128
#define NT 512
#define NT1 513
#define NS 64
#define NU 512

#define CIOG_BYTES ((size_t)NT1 * NBATCH * NU * 4)     // [t][b][u] packed bf16 pair: 134,479,872
#define HBUF_BYTES ((size_t)2 * NBATCH * NU * 2)       // double-buffered h, bf16: 262,144
#define FLAGS_BYTES ((size_t)128 * 16 * 4)             // one flag per (ring,uc), 64B-isolated: 8,192
#define YPART_BYTES ((size_t)NT1 * NBATCH * 32 * 4)    // y partials [t][b][uc] f32: 8,404,992

typedef __attribute__((ext_vector_type(8))) short short8_t;
typedef __attribute__((ext_vector_type(4))) float f32x4;

__device__ __forceinline__ float sigf(float z) {
    return 1.0f / (1.0f + __expf(-z));
}
__device__ __forceinline__ float tanh_fast(float z) {
    return 2.0f / (1.0f + __expf(-2.0f * z)) - 1.0f;
}
__device__ __forceinline__ uint32_t bf16_top(float f) {   // RNE, result in top 16 bits
    uint32_t u = __float_as_uint(f);
    u += 0x7FFFu + ((u >> 16) & 1u);
    return u & 0xFFFF0000u;
}
__device__ __forceinline__ float f_from_lo(uint32_t p) { return __uint_as_float(p << 16); }
__device__ __forceinline__ float f_from_hi(uint32_t p) { return __uint_as_float(p & 0xFFFF0000u); }

// ---------------------------------------------------------------------------
// ff_kernel: feedforward gates for all (b,t) -> packed bf16 (ci lo, og hi).
// Same math as rounds 1-4 (validated); output layout now t-major [t][b][u]
// so the recurrence reads a contiguous 64B row per (t,b).
// ---------------------------------------------------------------------------
__global__ __launch_bounds__(512) void ff_kernel(
    const float* __restrict__ states, const int* __restrict__ actions,
    const float* __restrict__ W_ci, const float* __restrict__ b_ci,
    const float* __restrict__ W_og, const float* __restrict__ b_og,
    uint32_t* __restrict__ ciog)
{
    __shared__ __align__(16) float sh_s[32][64];
    __shared__ int sh_a[32];
    const int tid = threadIdx.x;
    const int b = blockIdx.x / 17;
    const int t0 = (blockIdx.x % 17) * 32;
    const int tcnt = (t0 + 32 <= NT1) ? 32 : (NT1 - t0);

    const float* sp = states + ((size_t)b * NT1 + t0) * NS;
    for (int j = tid; j < tcnt * 16; j += 512) {
        const float4 v = *(const float4*)(sp + j * 4);
        *(float4*)&sh_s[j >> 4][(j & 15) * 4] = v;
    }
    for (int tt = tid; tt < tcnt; tt += 512) {
        const int t = t0 + tt;
        sh_a[tt] = (t < NT) ? actions[b * NT + t] : -1;
    }
    __syncthreads();

    const int u = tid;
    float accc[32], acco[32];
    const float bc = b_ci[u], bo = b_og[u];
    #pragma unroll
    for (int tt = 0; tt < 32; ++tt) { accc[tt] = bc; acco[tt] = bo; }

    for (int i = 0; i < NS; ++i) {
        const float wc = W_ci[(size_t)i * NU + u];
        const float wo = W_og[(size_t)i * NU + u];
        #pragma unroll
        for (int tt = 0; tt < 32; ++tt) {
            const float s = sh_s[tt][i];
            accc[tt] = fmaf(s, wc, accc[tt]);
            acco[tt] = fmaf(s, wo, acco[tt]);
        }
    }
    #pragma unroll
    for (int tt = 0; tt < 32; ++tt) {
        if (tt < tcnt) {
            float zc = accc[tt], zo = acco[tt];
            const int a = sh_a[tt];
            if (a >= 0) {
                zc += W_ci[(size_t)(NS + a) * NU + u];
                zo += W_og[(size_t)(NS + a) * NU + u];
            }
            const float ci = tanh_fast(zc);
            const float og = sigf(zo);
            ciog[((size_t)(t0 + tt) * NBATCH + b) * NU + u] = bf16_top(og) | (bf16_top(ci) >> 16);
        }
    }
}

// ---------------------------------------------------------------------------
// rec_sync: multi-CU recurrence. 128 WGs x 512 thr = 4 rings x 32 WGs.
// Ring q owns batches [32q, +32); WG (q,uc) owns u-slice [16uc, +16) and its
// W_ig column slice as register-resident B-fragments (16 VGPRs/lane).
// Per step: waves poll only the 8 chunk-flags their K-quarter needs
// (agent-scope relaxed spin + acquire fence), read h_t from a global
// double-buffered bf16 h-buffer directly as MFMA A-fragments, 4 MFMAs/wave,
// 4-way LDS reduce, per-thread gate math (c in a register), write the 1KB
// h_{t+1} chunk, release-fence, bump flag. 2-deep h buffer is hazard-free:
// observing all ring flags >= t implies every consumer finished reading
// h_{t-1}, so overwriting buf[(t+1)&1] is safe.
// ---------------------------------------------------------------------------
__global__ __launch_bounds__(512) void rec_sync(
    const float* __restrict__ W_ig, const float* __restrict__ b_ig,
    const float* __restrict__ W_lin,
    const uint32_t* __restrict__ ciog,   // [t][b][u]
    short* __restrict__ hbuf,            // [2][128][512] bf16
    int* __restrict__ flags,             // [128] stride-16 ints
    float* __restrict__ ypart)           // [t][b][32] f32
{
    __shared__ float zpart[4][32][17];

    const int tid  = threadIdx.x;
    const int lane = tid & 63;
    const int wv   = tid >> 6;
    const int kq   = wv & 3;        // K-quarter of this wave
    const int mf   = wv >> 2;       // M-fragment (16 batches) of this wave
    const int r16  = lane & 15;
    const int kg   = lane >> 4;

    const int q  = blockIdx.x & 3;  // ring (batch quarter)
    const int uc = blockIdx.x >> 2; // u-chunk 0..31
    const int u0 = uc << 4;
    const int b0 = q << 5;

    // ---- one-time: B-fragments of W_ig column slice (k in [kq*128,+128), u = u0+r16)
    short8_t wreg[4];
    #pragma unroll
    for (int kf = 0; kf < 4; ++kf) {
        #pragma unroll
        for (int j = 0; j < 8; ++j) {
            const int k = kq * 128 + kf * 32 + kg * 8 + j;
            wreg[kf][j] = (short)(bf16_top(W_ig[(size_t)k * NU + u0 + r16]) >> 16);
        }
    }

    // gate-phase constants: thread owns (b = tid>>4, u = tid&15)
    const int gb = tid >> 4;
    const int gu = tid & 15;
    const float big_ = b_ig[u0 + gu];
    const float wlin = W_lin[u0 + gu];
    float c = 0.0f;

    int* myflag = flags + (q * 32 + kq * 8 + (lane & 7)) * 16;
    int* ourflag = flags + (q * 32 + uc) * 16;

    for (int t = 0; t < NT1; ++t) {
        // ---- poll: the 8 producer chunks this wave's K-quarter reads ----
        if (t > 0) {
            int spin = 0;
            int fv;
            do {
                fv = __hip_atomic_load(myflag, __ATOMIC_RELAXED, __HIP_MEMORY_SCOPE_AGENT);
            } while (__any(fv < t) && ++spin < (1 << 22));
        }
        __threadfence();   // acquire: make producers' h_t stores visible

        // prefetch this thread's ci/og (consumed in gate phase)
        const uint32_t pk = ciog[((size_t)t * NBATCH + b0 + gb) * NU + u0 + gu];

        // ---- MFMA: z partial for (mf batches, kq K-quarter) ----
        const short* hr = hbuf + ((size_t)(t & 1) * NBATCH + b0 + mf * 16 + r16) * NU
                          + kq * 128 + kg * 8;
        f32x4 acc = {0.f, 0.f, 0.f, 0.f};
        #pragma unroll
        for (int kf = 0; kf < 4; ++kf) {
            const short8_t a = *(const short8_t*)(hr + kf * 32);
            acc = __builtin_amdgcn_mfma_f32_16x16x32_bf16(a, wreg[kf], acc, 0, 0, 0);
        }
        // D-layout (validated r2-r4): col = lane&15 (=u), row = (lane>>4)*4 + j (=b within tile)
        #pragma unroll
        for (int j = 0; j < 4; ++j) {
            zpart[kq][mf * 16 + kg * 4 + j][r16] = acc[j];
        }
        __syncthreads();

        // ---- gate phase: one (b,u) per thread; c lives in a register ----
        float z = big_;
        #pragma unroll
        for (int k4 = 0; k4 < 4; ++k4) z += zpart[k4][gb][gu];
        const float igv = sigf(z);
        c = fmaf(f_from_lo(pk), igv, c);
        const float hv = c * f_from_hi(pk);
        hbuf[((size_t)((t + 1) & 1) * NBATCH + b0 + gb) * NU + u0 + gu] =
            (short)(bf16_top(hv) >> 16);

        // y partial: reduce over this chunk's 16 u's
        float yv = hv * wlin;
        yv += __shfl_xor(yv, 1);
        yv += __shfl_xor(yv, 2);
        yv += __shfl_xor(yv, 4);
        yv += __shfl_xor(yv, 8);
        if (gu == 0) ypart[((size_t)t * NBATCH + b0 + gb) * 32 + uc] = yv;

        __syncthreads();   // all h stores drained (vmcnt(0) per thread) before flag
        if (tid == 0) {
            __threadfence();  // release: publish h_{t+1} device-wide
            __hip_atomic_store(ourflag, t + 1, __ATOMIC_RELEASE, __HIP_MEMORY_SCOPE_AGENT);
        }
    }
}

// ---------------------------------------------------------------------------
// yreduce: out[b][t] = b_lin + sum_uc ypart[t][b][uc]   (deterministic order)
// ---------------------------------------------------------------------------
__global__ __launch_bounds__(256) void yreduce(
    const float* __restrict__ ypart, const float* __restrict__ b_lin,
    float* __restrict__ out)
{
    const int g = blockIdx.x * 256 + threadIdx.x;   // g = t*128 + b
    if (g >= NT1 * NBATCH) return;
    const float* p = ypart + (size_t)g * 32;
    float s = b_lin[0];
    #pragma unroll
    for (int i = 0; i < 32; ++i) s += p[i];
    const int b = g & 127, t = g >> 7;
    out[(size_t)b * NT1 + t] = s;
}

// ---------------------------------------------------------------------------
// Fallback (ws too small): validated round-1 kernel, recomputes gates in-loop.
// ---------------------------------------------------------------------------
__device__ __forceinline__ void fma4(float4& acc, const float4 w, const float s) {
    acc.x = fmaf(w.x, s, acc.x);
    acc.y = fmaf(w.y, s, acc.y);
    acc.z = fmaf(w.z, s, acc.z);
    acc.w = fmaf(w.w, s, acc.w);
}

__global__ __launch_bounds__(512) void rec_fallback(
    const float* __restrict__ states, const int* __restrict__ actions,
    const float* __restrict__ W_ci, const float* __restrict__ b_ci,
    const float* __restrict__ W_ig, const float* __restrict__ b_ig,
    const float* __restrict__ W_og, const float* __restrict__ b_og,
    const float* __restrict__ W_lin, const float* __restrict__ b_lin,
    float* __restrict__ out)
{
    __shared__ __align__(16) float h_lds[2][NU];
    __shared__ __align__(16) float part[4][2][NU];
    __shared__ float ysum[8][2];
    __shared__ float x_lds[2][NS];
    __shared__ int a_lds[2];

    const int tid = threadIdx.x;
    const int b0 = blockIdx.x * 2;
    const int uq = tid & 127;
    const int kq = tid >> 7;
    const int k0 = kq << 7;

    h_lds[0][tid] = 0.0f;
    h_lds[1][tid] = 0.0f;
    float c0 = 0.0f, c1 = 0.0f;
    const float wlin = W_lin[tid];
    const float big_ = b_ig[tid];
    const float blin = b_lin[0];
    const float bc = b_ci[tid], bo = b_og[tid];
    __syncthreads();

    for (int t = 0; t < NT1; ++t) {
        if (tid < 128) {
            const int bb = tid >> 6, i = tid & 63;
            x_lds[bb][i] = states[((size_t)(b0 + bb) * NT1 + t) * NS + i];
        } else if (tid < 130) {
            const int bb = tid - 128;
            a_lds[bb] = (t < NT) ? actions[(b0 + bb) * NT + t] : -1;
        }

        float4 a0 = make_float4(0.f, 0.f, 0.f, 0.f);
        float4 a1 = make_float4(0.f, 0.f, 0.f, 0.f);
        for (int kk = 0; kk < 128; kk += 4) {
            const int k = k0 + kk;
            const float4 h0v = *(const float4*)&h_lds[0][k];
            const float4 h1v = *(const float4*)&h_lds[1][k];
            const float* wr = W_ig + (size_t)k * NU + (uq << 2);
            const float4 w0 = *(const float4*)(wr);
            const float4 w1 = *(const float4*)(wr + NU);
            const float4 w2 = *(const float4*)(wr + 2 * NU);
            const float4 w3 = *(const float4*)(wr + 3 * NU);
            fma4(a0, w0, h0v.x); fma4(a1, w0, h1v.x);
            fma4(a0, w1, h0v.y); fma4(a1, w1, h1v.y);
            fma4(a0, w2, h0v.z); fma4(a1, w2, h1v.z);
            fma4(a0, w3, h0v.w); fma4(a1, w3, h1v.w);
        }
        *(float4*)&part[kq][0][uq << 2] = a0;
        *(float4*)&part[kq][1][uq << 2] = a1;
        __syncthreads();

        float z0 = big_, z1 = big_;
        #pragma unroll
        for (int q = 0; q < 4; ++q) { z0 += part[q][0][tid]; z1 += part[q][1][tid]; }

        float zc0 = bc, zo0 = bo, zc1 = bc, zo1 = bo;
        for (int i = 0; i < NS; ++i) {
            const float wc = W_ci[(size_t)i * NU + tid];
            const float wo = W_og[(size_t)i * NU + tid];
            const float s0v = x_lds[0][i];
            const float s1v = x_lds[1][i];
            zc0 = fmaf(s0v, wc, zc0); zo0 = fmaf(s0v, wo, zo0);
            zc1 = fmaf(s1v, wc, zc1); zo1 = fmaf(s1v, wo, zo1);
        }
        const int a0i = a_lds[0], a1i = a_lds[1];
        if (a0i >= 0) { zc0 += W_ci[(size_t)(NS + a0i) * NU + tid]; zo0 += W_og[(size_t)(NS + a0i) * NU + tid]; }
        if (a1i >= 0) { zc1 += W_ci[(size_t)(NS + a1i) * NU + tid]; zo1 += W_og[(size_t)(NS + a1i) * NU + tid]; }
        const float ci0 = tanh_fast(zc0), og0 = sigf(zo0);
        const float ci1 = tanh_fast(zc1), og1 = sigf(zo1);

        const float ig0 = sigf(z0), ig1 = sigf(z1);
        c0 = fmaf(ci0, ig0, c0);
        c1 = fmaf(ci1, ig1, c1);
        const float h0 = c0 * og0, h1 = c1 * og1;
        h_lds[0][tid] = h0;
        h_lds[1][tid] = h1;

        float y0 = h0 * wlin, y1 = h1 * wlin;
        #pragma unroll
        for (int off = 32; off > 0; off >>= 1) {
            y0 += __shfl_xor(y0, off);
            y1 += __shfl_xor(y1, off);
        }
        if ((tid & 63) == 0) { ysum[tid >> 6][0] = y0; ysum[tid >> 6][1] = y1; }
        __syncthreads();

        if (tid < 2) {
            float y = blin;
            #pragma unroll
            for (int w = 0; w < 8; ++w) y += ysum[w][tid];
            out[(size_t)(b0 + tid) * NT1 + t] = y;
        }
    }
}

extern "C" void kernel_launch(void* const* d_in, const int* in_sizes, int n_in,
                              void* d_out, int out_size, void* d_ws, size_t ws_size,
                              hipStream_t stream) {
    const float* states = (const float*)d_in[0];
    const int*   actions= (const int*)d_in[1];
    const float* W_ci = (const float*)d_in[2];
    const float* b_ci = (const float*)d_in[3];
    const float* W_ig = (const float*)d_in[4];
    const float* b_ig = (const float*)d_in[5];
    const float* W_og = (const float*)d_in[6];
    const float* b_og = (const float*)d_in[7];
    const float* W_lin= (const float*)d_in[8];
    const float* b_lin= (const float*)d_in[9];
    float* out = (float*)d_out;

    const size_t need = CIOG_BYTES + HBUF_BYTES + FLAGS_BYTES + YPART_BYTES;  // ~143.2 MB
    if (ws_size >= need) {
        char* base = (char*)d_ws;
        uint32_t* ciog = (uint32_t*)base;
        short* hbuf    = (short*)(base + CIOG_BYTES);
        int* flags     = (int*)(base + CIOG_BYTES + HBUF_BYTES);
        float* ypart   = (float*)(base + CIOG_BYTES + HBUF_BYTES + FLAGS_BYTES);

        // h_0 = 0 and all flags = 0, re-established on every (graph-replayed) call
        hipMemsetAsync(base + CIOG_BYTES, 0, HBUF_BYTES + FLAGS_BYTES, stream);

        ff_kernel<<<dim3(NBATCH * 17), dim3(512), 0, stream>>>(
            states, actions, W_ci, b_ci, W_og, b_og, ciog);
        rec_sync<<<dim3(128), dim3(512), 0, stream>>>(
            W_ig, b_ig, W_lin, ciog, hbuf, flags, ypart);
        yreduce<<<dim3((NT1 * NBATCH + 255) / 256), dim3(256), 0, stream>>>(
            ypart, b_lin, out);
    } else {
        rec_fallback<<<dim3(NBATCH / 2), dim3(512), 0, stream>>>(
            states, actions, W_ci, b_ci, W_ig, b_ig, W_og, b_og, W_lin, b_lin, out);
    }
}

// Round 6
// 4910.191 us; speedup vs baseline: 2.3274x; 2.3274x over previous
//
#include <hip/hip_runtime.h>
#include <cstdint>

#define NBATCH 128
#define NT 512
#define NT1 513
#define NS 64
#define NU 512
#define NBW 16                               // batches per workgroup
#define KF_SHORTS (8 * 4 * 64 * 8)           // shorts per kf across a WG = 16384
#define KF_V8 (KF_SHORTS / 8)                // short8 per kf = 2048
#define PACK_SHORTS (16 * KF_SHORTS)         // 262144 shorts = 512KB
#define CIOG_BYTES ((size_t)NT1 * NBATCH * NU * 4)   // [t][b][u]: 134,479,872
#define DYN_LDS (2 * KF_SHORTS * 2)          // 2 kf of W in LDS = 65536 B

typedef __attribute__((ext_vector_type(8))) short short8_t;
typedef __attribute__((ext_vector_type(4))) float f32x4;

__device__ __forceinline__ float sigf(float z) {
    return 1.0f / (1.0f + __expf(-z));
}
__device__ __forceinline__ float tanh_fast(float z) {
    return 2.0f / (1.0f + __expf(-2.0f * z)) - 1.0f;
}
__device__ __forceinline__ uint32_t bf16_top(float f) {   // RNE, result in top 16 bits
    uint32_t u = __float_as_uint(f);
    u += 0x7FFFu + ((u >> 16) & 1u);
    return u & 0xFFFF0000u;
}
__device__ __forceinline__ float f_from_lo(uint32_t p) { return __uint_as_float(p << 16); }
__device__ __forceinline__ float f_from_hi(uint32_t p) { return __uint_as_float(p & 0xFFFF0000u); }

// ---------------------------------------------------------------------------
// pack_kernel: one-time reorder of W_ig (f32 [k][u]) into bf16 MFMA-fragment
// order pack[kf][wv][nf][lane][j] (validated rounds 3-4).
// ---------------------------------------------------------------------------
__global__ __launch_bounds__(512) void pack_kernel(
    const float* __restrict__ W_ig, short* __restrict__ pack)
{
    const int g = blockIdx.x * 512 + threadIdx.x;   // 32768 threads
    const int lane = g & 63;
    const int nf = (g >> 6) & 3;
    const int wv = (g >> 8) & 7;
    const int kf = g >> 11;
    const int r16 = lane & 15, kg = lane >> 4;
    const int u = wv * 64 + nf * 16 + r16;
    const int kb = kf * 32 + kg * 8;
    short8_t w;
    #pragma unroll
    for (int j = 0; j < 8; ++j) {
        w[j] = (short)(bf16_top(W_ig[(size_t)(kb + j) * NU + u]) >> 16);
    }
    *(short8_t*)(pack + (size_t)g * 8) = w;
}

// ---------------------------------------------------------------------------
// ff_kernel: feedforward gates -> packed bf16 (ci lo, og hi), t-major
// layout [t][b][u] (validated round 5).
// ---------------------------------------------------------------------------
__global__ __launch_bounds__(512) void ff_kernel(
    const float* __restrict__ states, const int* __restrict__ actions,
    const float* __restrict__ W_ci, const float* __restrict__ b_ci,
    const float* __restrict__ W_og, const float* __restrict__ b_og,
    uint32_t* __restrict__ ciog)
{
    __shared__ __align__(16) float sh_s[32][64];
    __shared__ int sh_a[32];
    const int tid = threadIdx.x;
    const int b = blockIdx.x / 17;
    const int t0 = (blockIdx.x % 17) * 32;
    const int tcnt = (t0 + 32 <= NT1) ? 32 : (NT1 - t0);

    const float* sp = states + ((size_t)b * NT1 + t0) * NS;
    for (int j = tid; j < tcnt * 16; j += 512) {
        const float4 v = *(const float4*)(sp + j * 4);
        *(float4*)&sh_s[j >> 4][(j & 15) * 4] = v;
    }
    for (int tt = tid; tt < tcnt; tt += 512) {
        const int t = t0 + tt;
        sh_a[tt] = (t < NT) ? actions[b * NT + t] : -1;
    }
    __syncthreads();

    const int u = tid;
    float accc[32], acco[32];
    const float bc = b_ci[u], bo = b_og[u];
    #pragma unroll
    for (int tt = 0; tt < 32; ++tt) { accc[tt] = bc; acco[tt] = bo; }

    for (int i = 0; i < NS; ++i) {
        const float wc = W_ci[(size_t)i * NU + u];
        const float wo = W_og[(size_t)i * NU + u];
        #pragma unroll
        for (int tt = 0; tt < 32; ++tt) {
            const float s = sh_s[tt][i];
            accc[tt] = fmaf(s, wc, accc[tt]);
            acco[tt] = fmaf(s, wo, acco[tt]);
        }
    }
    #pragma unroll
    for (int tt = 0; tt < 32; ++tt) {
        if (tt < tcnt) {
            float zc = accc[tt], zo = acco[tt];
            const int a = sh_a[tt];
            if (a >= 0) {
                zc += W_ci[(size_t)(NS + a) * NU + u];
                zo += W_og[(size_t)(NS + a) * NU + u];
            }
            const float ci = tanh_fast(zc);
            const float og = sigf(zo);
            ciog[((size_t)(t0 + tt) * NBATCH + b) * NU + u] = bf16_top(og) | (bf16_top(ci) >> 16);
        }
    }
}

// ---------------------------------------------------------------------------
// rec_mfma3: 8 independent WGs (16 batches each), per-step z = h @ W_ig via
// 64 MFMAs/wave. W supply: kf{0,1} in registers (32 VGPR), kf{2,3} in LDS
// (64KB), kf{4..15} streamed from L2 each step through a 2-slot rotating
// register pipeline (loads are h-independent; last two issues wrap into the
// next timestep). h double-buffered in LDS -> ONE barrier per step.
// Numerics identical to validated rounds 2-4.
// ---------------------------------------------------------------------------
__global__ __attribute__((amdgpu_waves_per_eu(2, 2))) __launch_bounds__(512)
void rec_mfma3(
    const short* __restrict__ pack,
    const float* __restrict__ b_ig, const float* __restrict__ W_lin,
    const float* __restrict__ b_lin,
    const uint32_t* __restrict__ ciog,   // [t][b][u]
    float* __restrict__ out)
{
    extern __shared__ __align__(16) char dynsm[];      // 64KB: W kf {2,3}
    __shared__ __align__(16) short hsh[2][NBW * NU];   // 2 x 16KB
    __shared__ float ysum[2][8][NBW];

    const int tid  = threadIdx.x;
    const int lane = tid & 63;
    const int wv   = tid >> 6;      // wave 0..7, owns u in [wv*64, +64)
    const int n0   = wv << 6;
    const int r16  = lane & 15;
    const int kg   = lane >> 4;
    const int b0   = blockIdx.x * NBW;

    const short8_t* pr = (const short8_t*)pack;
    #define PFRAG(KF_, NF_) (pr[(((KF_) * 8 + wv) * 4 + (NF_)) * 64 + lane])

    // ---- reg-resident kf 0,1 (32 VGPRs) ----
    short8_t wreg[2][4];
    #pragma unroll
    for (int kf = 0; kf < 2; ++kf) {
        #pragma unroll
        for (int nf = 0; nf < 4; ++nf) wreg[kf][nf] = PFRAG(kf, nf);
    }

    // ---- LDS-resident kf 2,3 (linear copy, layout == pack) ----
    short8_t* dl = (short8_t*)dynsm;
    {
        const short8_t* pl = pr + 2 * KF_V8;
        #pragma unroll
        for (int i = 0; i < 8; ++i) dl[i * 512 + tid] = pl[i * 512 + tid];
    }

    float big[4], wl[4];
    #pragma unroll
    for (int nf = 0; nf < 4; ++nf) {
        big[nf] = b_ig[n0 + nf * 16 + r16];
        wl[nf]  = W_lin[n0 + nf * 16 + r16];
    }
    const float blin = b_lin[0];

    for (int i = tid; i < NBW * NU; i += 512) hsh[0][i] = 0;

    float cst[4][4] = {{0.f,0.f,0.f,0.f},{0.f,0.f,0.f,0.f},
                       {0.f,0.f,0.f,0.f},{0.f,0.f,0.f,0.f}};

    const int amask = (r16 & 7) << 4;    // XOR swizzle (validated rounds 2-4)

    __syncthreads();

    // ---- stream prologue: sA <- kf4, sB <- kf5 ----
    short8_t sA[4], sB[4];
    #define LD4(S, KF) { (S)[0] = PFRAG(KF, 0); (S)[1] = PFRAG(KF, 1); \
                         (S)[2] = PFRAG(KF, 2); (S)[3] = PFRAG(KF, 3); }
    LD4(sA, 4)
    LD4(sB, 5)

    for (int t = 0; t < NT1; ++t) {
        const char* hb = (const char*)hsh[t & 1];
        char* hw = (char*)hsh[(t + 1) & 1];

        // ci/og prefetch for this step (consumed in gate phase)
        uint32_t pk[4][4];
        const uint32_t* cg = ciog + (size_t)t * (NBATCH * NU);
        #pragma unroll
        for (int nf = 0; nf < 4; ++nf) {
            #pragma unroll
            for (int j = 0; j < 4; ++j)
                pk[nf][j] = cg[(size_t)(b0 + kg * 4 + j) * NU + n0 + nf * 16 + r16];
        }

        // previous step's output row (ysum double-buffered)
        if (t > 0 && wv == 0 && lane < NBW) {
            float y = blin;
            #pragma unroll
            for (int w8 = 0; w8 < 8; ++w8) y += ysum[(t - 1) & 1][w8][lane];
            out[(size_t)(b0 + lane) * NT1 + (t - 1)] = y;
        }

        f32x4 acc[4];
        #pragma unroll
        for (int nf = 0; nf < 4; ++nf) { acc[nf][0]=0.f; acc[nf][1]=0.f; acc[nf][2]=0.f; acc[nf][3]=0.f; }

        #define AFRAG(KF) (*(const short8_t*)(hb + r16 * 1024 + ((((KF) * 64) + kg * 16) ^ amask)))
        #define MF4(KF, W) { const short8_t a_ = AFRAG(KF); \
            acc[0] = __builtin_amdgcn_mfma_f32_16x16x32_bf16(a_, (W)[0], acc[0], 0, 0, 0); \
            acc[1] = __builtin_amdgcn_mfma_f32_16x16x32_bf16(a_, (W)[1], acc[1], 0, 0, 0); \
            acc[2] = __builtin_amdgcn_mfma_f32_16x16x32_bf16(a_, (W)[2], acc[2], 0, 0, 0); \
            acc[3] = __builtin_amdgcn_mfma_f32_16x16x32_bf16(a_, (W)[3], acc[3], 0, 0, 0); }

        // ---- reg kf 0,1 ----
        MF4(0, wreg[0])
        MF4(1, wreg[1])

        // ---- LDS kf 2,3 ----
        #pragma unroll
        for (int kf = 0; kf < 2; ++kf) {
            short8_t wt[4];
            #pragma unroll
            for (int nf = 0; nf < 4; ++nf)
                wt[nf] = dl[((kf * 8 + wv) * 4 + nf) * 64 + lane];
            MF4(2 + kf, wt)
        }

        // ---- stream kf 4..15, 2-slot rotation; tail wraps to next step ----
        MF4(4,  sA)  LD4(sA, 6)
        MF4(5,  sB)  LD4(sB, 7)
        MF4(6,  sA)  LD4(sA, 8)
        MF4(7,  sB)  LD4(sB, 9)
        MF4(8,  sA)  LD4(sA, 10)
        MF4(9,  sB)  LD4(sB, 11)
        MF4(10, sA)  LD4(sA, 12)
        MF4(11, sB)  LD4(sB, 13)
        MF4(12, sA)  LD4(sA, 14)
        MF4(13, sB)  LD4(sB, 15)
        MF4(14, sA)  LD4(sA, 4)    // next step's kf4
        MF4(15, sB)  LD4(sB, 5)    // next step's kf5
        #undef MF4
        #undef AFRAG

        // ---- gate phase: c update, h_{t+1} write into other buffer ----
        float yp[4] = {0.f, 0.f, 0.f, 0.f};
        #pragma unroll
        for (int nf = 0; nf < 4; ++nf) {
            const int u2 = (n0 + nf * 16 + r16) * 2;
            #pragma unroll
            for (int j = 0; j < 4; ++j) {
                const int b = kg * 4 + j;
                const float z   = acc[nf][j] + big[nf];
                const float igv = sigf(z);
                const uint32_t p = pk[nf][j];
                cst[nf][j] = fmaf(f_from_lo(p), igv, cst[nf][j]);
                const float hv = cst[nf][j] * f_from_hi(p);
                yp[j] = fmaf(hv, wl[nf], yp[j]);
                const int wb = b * 1024 + (u2 ^ ((b & 7) << 4));
                *(short*)(hw + wb) = (short)(bf16_top(hv) >> 16);
            }
        }

        #pragma unroll
        for (int m = 1; m <= 8; m <<= 1) {
            yp[0] += __shfl_xor(yp[0], m);
            yp[1] += __shfl_xor(yp[1], m);
            yp[2] += __shfl_xor(yp[2], m);
            yp[3] += __shfl_xor(yp[3], m);
        }
        if (r16 == 0) {
            #pragma unroll
            for (int j = 0; j < 4; ++j) ysum[t & 1][wv][kg * 4 + j] = yp[j];
        }

        __syncthreads();   // single barrier: h_{t+1} + ysum visible
    }

    if (wv == 0 && lane < NBW) {
        float y = blin;
        #pragma unroll
        for (int w8 = 0; w8 < 8; ++w8) y += ysum[0][w8][lane];
        out[(size_t)(b0 + lane) * NT1 + NT] = y;
    }
    #undef LD4
    #undef PFRAG
}

// ---------------------------------------------------------------------------
// Fallback (ws too small): validated round-1 kernel.
// ---------------------------------------------------------------------------
__device__ __forceinline__ void fma4(float4& acc, const float4 w, const float s) {
    acc.x = fmaf(w.x, s, acc.x);
    acc.y = fmaf(w.y, s, acc.y);
    acc.z = fmaf(w.z, s, acc.z);
    acc.w = fmaf(w.w, s, acc.w);
}

__global__ __launch_bounds__(512) void rec_fallback(
    const float* __restrict__ states, const int* __restrict__ actions,
    const float* __restrict__ W_ci, const float* __restrict__ b_ci,
    const float* __restrict__ W_ig, const float* __restrict__ b_ig,
    const float* __restrict__ W_og, const float* __restrict__ b_og,
    const float* __restrict__ W_lin, const float* __restrict__ b_lin,
    float* __restrict__ out)
{
    __shared__ __align__(16) float h_lds[2][NU];
    __shared__ __align__(16) float part[4][2][NU];
    __shared__ float ysum[8][2];
    __shared__ float x_lds[2][NS];
    __shared__ int a_lds[2];

    const int tid = threadIdx.x;
    const int b0 = blockIdx.x * 2;
    const int uq = tid & 127;
    const int kq = tid >> 7;
    const int k0 = kq << 7;

    h_lds[0][tid] = 0.0f;
    h_lds[1][tid] = 0.0f;
    float c0 = 0.0f, c1 = 0.0f;
    const float wlin = W_lin[tid];
    const float big_ = b_ig[tid];
    const float blin = b_lin[0];
    const float bc = b_ci[tid], bo = b_og[tid];
    __syncthreads();

    for (int t = 0; t < NT1; ++t) {
        if (tid < 128) {
            const int bb = tid >> 6, i = tid & 63;
            x_lds[bb][i] = states[((size_t)(b0 + bb) * NT1 + t) * NS + i];
        } else if (tid < 130) {
            const int bb = tid - 128;
            a_lds[bb] = (t < NT) ? actions[(b0 + bb) * NT + t] : -1;
        }

        float4 a0 = make_float4(0.f, 0.f, 0.f, 0.f);
        float4 a1 = make_float4(0.f, 0.f, 0.f, 0.f);
        for (int kk = 0; kk < 128; kk += 4) {
            const int k = k0 + kk;
            const float4 h0v = *(const float4*)&h_lds[0][k];
            const float4 h1v = *(const float4*)&h_lds[1][k];
            const float* wr = W_ig + (size_t)k * NU + (uq << 2);
            const float4 w0 = *(const float4*)(wr);
            const float4 w1 = *(const float4*)(wr + NU);
            const float4 w2 = *(const float4*)(wr + 2 * NU);
            const float4 w3 = *(const float4*)(wr + 3 * NU);
            fma4(a0, w0, h0v.x); fma4(a1, w0, h1v.x);
            fma4(a0, w1, h0v.y); fma4(a1, w1, h1v.y);
            fma4(a0, w2, h0v.z); fma4(a1, w2, h1v.z);
            fma4(a0, w3, h0v.w); fma4(a1, w3, h1v.w);
        }
        *(float4*)&part[kq][0][uq << 2] = a0;
        *(float4*)&part[kq][1][uq << 2] = a1;
        __syncthreads();

        float z0 = big_, z1 = big_;
        #pragma unroll
        for (int q = 0; q < 4; ++q) { z0 += part[q][0][tid]; z1 += part[q][1][tid]; }

        float zc0 = bc, zo0 = bo, zc1 = bc, zo1 = bo;
        for (int i = 0; i < NS; ++i) {
            const float wc = W_ci[(size_t)i * NU + tid];
            const float wo = W_og[(size_t)i * NU + tid];
            const float s0v = x_lds[0][i];
            const float s1v = x_lds[1][i];
            zc0 = fmaf(s0v, wc, zc0); zo0 = fmaf(s0v, wo, zo0);
            zc1 = fmaf(s1v, wc, zc1); zo1 = fmaf(s1v, wo, zo1);
        }
        const int a0i = a_lds[0], a1i = a_lds[1];
        if (a0i >= 0) { zc0 += W_ci[(size_t)(NS + a0i) * NU + tid]; zo0 += W_og[(size_t)(NS + a0i) * NU + tid]; }
        if (a1i >= 0) { zc1 += W_ci[(size_t)(NS + a1i) * NU + tid]; zo1 += W_og[(size_t)(NS + a1i) * NU + tid]; }
        const float ci0 = tanh_fast(zc0), og0 = sigf(zo0);
        const float ci1 = tanh_fast(zc1), og1 = sigf(zo1);

        const float ig0 = sigf(z0), ig1 = sigf(z1);
        c0 = fmaf(ci0, ig0, c0);
        c1 = fmaf(ci1, ig1, c1);
        const float h0 = c0 * og0, h1 = c1 * og1;
        h_lds[0][tid] = h0;
        h_lds[1][tid] = h1;

        float y0 = h0 * wlin, y1 = h1 * wlin;
        #pragma unroll
        for (int off = 32; off > 0; off >>= 1) {
            y0 += __shfl_xor(y0, off);
            y1 += __shfl_xor(y1, off);
        }
        if ((tid & 63) == 0) { ysum[tid >> 6][0] = y0; ysum[tid >> 6][1] = y1; }
        __syncthreads();

        if (tid < 2) {
            float y = blin;
            #pragma unroll
            for (int w = 0; w < 8; ++w) y += ysum[w][tid];
            out[(size_t)(b0 + tid) * NT1 + t] = y;
        }
    }
}

extern "C" void kernel_launch(void* const* d_in, const int* in_sizes, int n_in,
                              void* d_out, int out_size, void* d_ws, size_t ws_size,
                              hipStream_t stream) {
    const float* states = (const float*)d_in[0];
    const int*   actions= (const int*)d_in[1];
    const float* W_ci = (const float*)d_in[2];
    const float* b_ci = (const float*)d_in[3];
    const float* W_ig = (const float*)d_in[4];
    const float* b_ig = (const float*)d_in[5];
    const float* W_og = (const float*)d_in[6];
    const float* b_og = (const float*)d_in[7];
    const float* W_lin= (const float*)d_in[8];
    const float* b_lin= (const float*)d_in[9];
    float* out = (float*)d_out;

    const size_t need = CIOG_BYTES + (size_t)PACK_SHORTS * 2;   // ~135 MB
    if (ws_size >= need) {
        uint32_t* ciog = (uint32_t*)d_ws;
        short* pack = (short*)((char*)d_ws + CIOG_BYTES);

        (void)hipFuncSetAttribute((const void*)rec_mfma3,
                                  hipFuncAttributeMaxDynamicSharedMemorySize, DYN_LDS);

        pack_kernel<<<dim3(64), dim3(512), 0, stream>>>(W_ig, pack);
        ff_kernel<<<dim3(NBATCH * 17), dim3(512), 0, stream>>>(
            states, actions, W_ci, b_ci, W_og, b_og, ciog);
        rec_mfma3<<<dim3(NBATCH / NBW), dim3(512), DYN_LDS, stream>>>(
            pack, b_ig, W_lin, b_lin, ciog, out);
    } else {
        rec_fallback<<<dim3(NBATCH / 2), dim3(512), 0, stream>>>(
            states, actions, W_ci, b_ci, W_ig, b_ig, W_og, b_og, W_lin, b_lin, out);
    }
}

// Round 8
// 3576.400 us; speedup vs baseline: 3.1954x; 1.3729x over previous
//
#include <hip/hip_runtime.h>
#include <cstdint>

#define NBATCH 128
#define NT 512
#define NT1 513
#define NS 64
#define NU 512
#define NBW 16                               // batches per workgroup
#define KFB 32768                            // bytes per kf slice (32 k x 512 u x 2B)
#define KF_SHORTS 16384
#define PACK_SHORTS (16 * KF_SHORTS)         // 512 KB
#define CIOG_BYTES ((size_t)NT1 * NBATCH * NU * 4)   // [t][b][u]: 134,479,872
#define SLOT_B 4096                          // per-wave per-slot bytes (one kf slice per wave)
#define DYN_LDS (8 * 3 * SLOT_B)             // 98304 B

typedef __attribute__((ext_vector_type(8))) short short8_t;
typedef __attribute__((ext_vector_type(4))) float f32x4;

__device__ __forceinline__ float sigf(float z) {
    return 1.0f / (1.0f + __expf(-z));
}
__device__ __forceinline__ float tanh_fast(float z) {
    return 2.0f / (1.0f + __expf(-2.0f * z)) - 1.0f;
}
__device__ __forceinline__ uint32_t bf16_top(float f) {   // RNE, result in top 16 bits
    uint32_t u = __float_as_uint(f);
    u += 0x7FFFu + ((u >> 16) & 1u);
    return u & 0xFFFF0000u;
}
__device__ __forceinline__ float f_from_lo(uint32_t p) { return __uint_as_float(p << 16); }
__device__ __forceinline__ float f_from_hi(uint32_t p) { return __uint_as_float(p & 0xFFFF0000u); }

// flat LDS pointer -> 32-bit LDS byte offset (low 32 bits of shared aperture)
__device__ __forceinline__ unsigned as3(const void* p) {
    return (unsigned)(uintptr_t)p;
}
// async global->LDS DMA, 16B/lane (wave writes uniform base + lane*16)
__device__ __forceinline__ void dma16(const void* g, void* l) {
    __builtin_amdgcn_global_load_lds(
        (const __attribute__((address_space(1))) void*)g,
        (__attribute__((address_space(3))) void*)l, 16, 0, 0);
}

// ---------------------------------------------------------------------------
// pack_kernel: one-time reorder of W_ig (f32 [k][u]) into bf16 MFMA-fragment
// order pack[kf][wv][nf][lane][j] (validated rounds 3-6).
// ---------------------------------------------------------------------------
__global__ __launch_bounds__(512) void pack_kernel(
    const float* __restrict__ W_ig, short* __restrict__ pack)
{
    const int g = blockIdx.x * 512 + threadIdx.x;   // 32768 threads
    const int lane = g & 63;
    const int nf = (g >> 6) & 3;
    const int wv = (g >> 8) & 7;
    const int kf = g >> 11;
    const int r16 = lane & 15, kg = lane >> 4;
    const int u = wv * 64 + nf * 16 + r16;
    const int kb = kf * 32 + kg * 8;
    short8_t w;
    #pragma unroll
    for (int j = 0; j < 8; ++j) {
        w[j] = (short)(bf16_top(W_ig[(size_t)(kb + j) * NU + u]) >> 16);
    }
    *(short8_t*)(pack + (size_t)g * 8) = w;
}

// ---------------------------------------------------------------------------
// ff_kernel: feedforward gates -> packed bf16 (ci lo, og hi), t-major [t][b][u]
// (validated rounds 5-6).
// ---------------------------------------------------------------------------
__global__ __launch_bounds__(512) void ff_kernel(
    const float* __restrict__ states, const int* __restrict__ actions,
    const float* __restrict__ W_ci, const float* __restrict__ b_ci,
    const float* __restrict__ W_og, const float* __restrict__ b_og,
    uint32_t* __restrict__ ciog)
{
    __shared__ __align__(16) float sh_s[32][64];
    __shared__ int sh_a[32];
    const int tid = threadIdx.x;
    const int b = blockIdx.x / 17;
    const int t0 = (blockIdx.x % 17) * 32;
    const int tcnt = (t0 + 32 <= NT1) ? 32 : (NT1 - t0);

    const float* sp = states + ((size_t)b * NT1 + t0) * NS;
    for (int j = tid; j < tcnt * 16; j += 512) {
        const float4 v = *(const float4*)(sp + j * 4);
        *(float4*)&sh_s[j >> 4][(j & 15) * 4] = v;
    }
    for (int tt = tid; tt < tcnt; tt += 512) {
        const int t = t0 + tt;
        sh_a[tt] = (t < NT) ? actions[b * NT + t] : -1;
    }
    __syncthreads();

    const int u = tid;
    float accc[32], acco[32];
    const float bc = b_ci[u], bo = b_og[u];
    #pragma unroll
    for (int tt = 0; tt < 32; ++tt) { accc[tt] = bc; acco[tt] = bo; }

    for (int i = 0; i < NS; ++i) {
        const float wc = W_ci[(size_t)i * NU + u];
        const float wo = W_og[(size_t)i * NU + u];
        #pragma unroll
        for (int tt = 0; tt < 32; ++tt) {
            const float s = sh_s[tt][i];
            accc[tt] = fmaf(s, wc, accc[tt]);
            acco[tt] = fmaf(s, wo, acco[tt]);
        }
    }
    #pragma unroll
    for (int tt = 0; tt < 32; ++tt) {
        if (tt < tcnt) {
            float zc = accc[tt], zo = acco[tt];
            const int a = sh_a[tt];
            if (a >= 0) {
                zc += W_ci[(size_t)(NS + a) * NU + u];
                zo += W_og[(size_t)(NS + a) * NU + u];
            }
            const float ci = tanh_fast(zc);
            const float og = sigf(zo);
            ciog[((size_t)(t0 + tt) * NBATCH + b) * NU + u] = bf16_top(og) | (bf16_top(ci) >> 16);
        }
    }
}

// ---------------------------------------------------------------------------
// rec_dma: 8 WGs x 512 thr, WG owns 16 batches, wave owns a 64-u slice.
// W supply: kf0 in VGPRs; kf1..15 streamed through a per-wave-private 3-slot
// LDS DMA pipeline (global_load_lds, counted vmcnt(8); DMAs stay in flight
// across the per-step barrier). Slot ds_reads are PER-LANE (base + lane*16)
// -- round 7's bug was a wave-uniform address here (broadcast of lane 0).
// h double-buffered in LDS, one raw s_barrier per step with lgkm-only drain.
// Numerics identical to validated rounds 2-6.
// ---------------------------------------------------------------------------
__global__ __launch_bounds__(512) void rec_dma(
    const short* __restrict__ pack,
    const float* __restrict__ b_ig, const float* __restrict__ W_lin,
    const float* __restrict__ b_lin,
    const uint32_t* __restrict__ ciog,   // [t][b][u]
    float* __restrict__ out)
{
    extern __shared__ __align__(16) char dynsm[];      // 96KB: 8 waves x 3 slots x 4KB
    __shared__ __align__(16) short hsh[2][NBW * NU];   // 2 x 16KB
    __shared__ float ysum[2][8][NBW];

    const int tid  = threadIdx.x;
    const int lane = tid & 63;
    const int wv   = tid >> 6;
    const int n0   = wv << 6;
    const int r16  = lane & 15;
    const int kg   = lane >> 4;
    const int b0   = blockIdx.x * NBW;

    // ---- kf0 resident in regs (16 VGPRs) ----
    const short8_t* pr = (const short8_t*)pack;
    short8_t wreg[4];
    #pragma unroll
    for (int nf = 0; nf < 4; ++nf) wreg[nf] = pr[(((0 * 8) + wv) * 4 + nf) * 64 + lane];

    float big[4], wl[4];
    #pragma unroll
    for (int nf = 0; nf < 4; ++nf) {
        big[nf] = b_ig[n0 + nf * 16 + r16];
        wl[nf]  = W_lin[n0 + nf * 16 + r16];
    }
    const float blin = b_lin[0];

    for (int i = tid; i < NBW * NU; i += 512) hsh[0][i] = 0;

    float cst[4][4] = {{0.f,0.f,0.f,0.f},{0.f,0.f,0.f,0.f},
                       {0.f,0.f,0.f,0.f},{0.f,0.f,0.f,0.f}};

    // ---- wave-private stream slots ----
    char* slA = dynsm + wv * (3 * SLOT_B);
    char* slB = slA + SLOT_B;
    char* slC = slA + 2 * SLOT_B;
    // READ addresses are per-lane (THE round-7 fix: + lane*16)
    unsigned aA = as3(slA) + (unsigned)(lane * 16);
    unsigned aB = as3(slB) + (unsigned)(lane * 16);
    unsigned aC = as3(slC) + (unsigned)(lane * 16);

    // per-lane global source base within a kf slice
    const char* gwv = (const char*)pack + wv * 4096 + (size_t)lane * 16;
    const char* gfirst = gwv + 1 * KFB;      // kf1
    const char* gcur;

    // prologue: kf1->A, kf2->B, kf3->C
    #pragma unroll
    for (int nf = 0; nf < 4; ++nf) dma16(gwv + 1 * KFB + nf * 1024, slA + nf * 1024);
    #pragma unroll
    for (int nf = 0; nf < 4; ++nf) dma16(gwv + 2 * KFB + nf * 1024, slB + nf * 1024);
    #pragma unroll
    for (int nf = 0; nf < 4; ++nf) dma16(gwv + 3 * KFB + nf * 1024, slC + nf * 1024);
    gcur = gwv + 4 * KFB;                    // next to fetch: kf4

    const unsigned amask = (r16 & 7) << 4;   // XOR swizzle (validated r2-r6)
    const unsigned kgx   = (unsigned)(kg << 4);

    __syncthreads();   // drains prologue DMAs once; h zero visible

    for (int t = 0; t < NT1; ++t) {
        const unsigned hb3 = as3(&hsh[t & 1][0]) + (unsigned)(r16 * 1024);
        const unsigned hw3 = as3(&hsh[(t + 1) & 1][0]);

        // ci/og for this step (C loads, issued before any PH DMA; FIFO-older
        // than all refills => vmcnt(8) can only over-drain, never under-drain)
        uint32_t pk[4][4];
        {
            const uint32_t* cg = ciog + (size_t)t * (NBATCH * NU);
            #pragma unroll
            for (int nf = 0; nf < 4; ++nf) {
                #pragma unroll
                for (int j = 0; j < 4; ++j)
                    pk[nf][j] = cg[(size_t)(b0 + kg * 4 + j) * NU + n0 + nf * 16 + r16];
            }
        }

        // previous step's output row (ysum double-buffered)
        if (t > 0 && wv == 0 && lane < NBW) {
            float y = blin;
            #pragma unroll
            for (int w8 = 0; w8 < 8; ++w8) y += ysum[(t - 1) & 1][w8][lane];
            out[(size_t)(b0 + lane) * NT1 + (t - 1)] = y;
        }

        f32x4 acc0 = {0.f,0.f,0.f,0.f}, acc1 = {0.f,0.f,0.f,0.f};
        f32x4 acc2 = {0.f,0.f,0.f,0.f}, acc3 = {0.f,0.f,0.f,0.f};

        // ---- reg kf0 ----
        {
            short8_t a_;
            const unsigned ha = hb3 + ((0u | kgx) ^ amask);
            asm volatile("ds_read_b128 %0, %1" : "=v"(a_) : "v"(ha));
            asm volatile("s_waitcnt lgkmcnt(0)");
            __builtin_amdgcn_sched_barrier(0);
            acc0 = __builtin_amdgcn_mfma_f32_16x16x32_bf16(a_, wreg[0], acc0, 0, 0, 0);
            acc1 = __builtin_amdgcn_mfma_f32_16x16x32_bf16(a_, wreg[1], acc1, 0, 0, 0);
            acc2 = __builtin_amdgcn_mfma_f32_16x16x32_bf16(a_, wreg[2], acc2, 0, 0, 0);
            acc3 = __builtin_amdgcn_mfma_f32_16x16x32_bf16(a_, wreg[3], acc3, 0, 0, 0);
        }

        // ---- streamed kf1..15: consume slot A, refill slot A, rotate ----
        #define PH(P) { \
            asm volatile("s_waitcnt vmcnt(8)"); \
            __builtin_amdgcn_sched_barrier(0); \
            short8_t w0_, w1_, w2_, w3_, a_; \
            asm volatile("ds_read_b128 %0, %1"             : "=v"(w0_) : "v"(aA)); \
            asm volatile("ds_read_b128 %0, %1 offset:1024" : "=v"(w1_) : "v"(aA)); \
            asm volatile("ds_read_b128 %0, %1 offset:2048" : "=v"(w2_) : "v"(aA)); \
            asm volatile("ds_read_b128 %0, %1 offset:3072" : "=v"(w3_) : "v"(aA)); \
            { const unsigned ha_ = hb3 + ((((unsigned)((P) << 6)) | kgx) ^ amask); \
              asm volatile("ds_read_b128 %0, %1" : "=v"(a_) : "v"(ha_)); } \
            asm volatile("s_waitcnt lgkmcnt(0)"); \
            __builtin_amdgcn_sched_barrier(0); \
            dma16(gcur,        slA); \
            dma16(gcur + 1024, slA + 1024); \
            dma16(gcur + 2048, slA + 2048); \
            dma16(gcur + 3072, slA + 3072); \
            __builtin_amdgcn_sched_barrier(0); \
            gcur = ((P) == 12) ? gfirst : (gcur + KFB); \
            acc0 = __builtin_amdgcn_mfma_f32_16x16x32_bf16(a_, w0_, acc0, 0, 0, 0); \
            acc1 = __builtin_amdgcn_mfma_f32_16x16x32_bf16(a_, w1_, acc1, 0, 0, 0); \
            acc2 = __builtin_amdgcn_mfma_f32_16x16x32_bf16(a_, w2_, acc2, 0, 0, 0); \
            acc3 = __builtin_amdgcn_mfma_f32_16x16x32_bf16(a_, w3_, acc3, 0, 0, 0); \
            { char* tp_ = slA; slA = slB; slB = slC; slC = tp_; \
              unsigned ta_ = aA; aA = aB; aB = aC; aC = ta_; } \
        }
        PH(1)  PH(2)  PH(3)  PH(4)  PH(5)
        PH(6)  PH(7)  PH(8)  PH(9)  PH(10)
        PH(11) PH(12) PH(13) PH(14) PH(15)
        #undef PH

        // ---- gate phase: c update, h_{t+1} asm-write into other buffer ----
        const f32x4* accp[4] = { &acc0, &acc1, &acc2, &acc3 };
        float yp[4] = {0.f, 0.f, 0.f, 0.f};
        #pragma unroll
        for (int nf = 0; nf < 4; ++nf) {
            const unsigned u2 = (unsigned)((n0 + nf * 16 + r16) * 2);
            #pragma unroll
            for (int j = 0; j < 4; ++j) {
                const int b = kg * 4 + j;
                const float z   = (*accp[nf])[j] + big[nf];
                const float igv = sigf(z);
                const uint32_t p = pk[nf][j];
                cst[nf][j] = fmaf(f_from_lo(p), igv, cst[nf][j]);
                const float hv = cst[nf][j] * f_from_hi(p);
                yp[j] = fmaf(hv, wl[nf], yp[j]);
                const unsigned wadr = hw3 + (unsigned)(b * 1024) + (u2 ^ ((unsigned)(b & 7) << 4));
                const unsigned hb16 = bf16_top(hv) >> 16;
                asm volatile("ds_write_b16 %0, %1" :: "v"(wadr), "v"(hb16));
            }
        }

        #pragma unroll
        for (int m = 1; m <= 8; m <<= 1) {
            yp[0] += __shfl_xor(yp[0], m);
            yp[1] += __shfl_xor(yp[1], m);
            yp[2] += __shfl_xor(yp[2], m);
            yp[3] += __shfl_xor(yp[3], m);
        }
        if (r16 == 0) {
            #pragma unroll
            for (int j = 0; j < 4; ++j) ysum[t & 1][wv][kg * 4 + j] = yp[j];
        }

        // step barrier: lgkm-only drain; stream DMAs stay in flight
        asm volatile("" ::: "memory");
        asm volatile("s_waitcnt lgkmcnt(0)");
        __builtin_amdgcn_s_barrier();
        asm volatile("" ::: "memory");
    }

    if (wv == 0 && lane < NBW) {
        float y = blin;
        #pragma unroll
        for (int w8 = 0; w8 < 8; ++w8) y += ysum[0][w8][lane];
        out[(size_t)(b0 + lane) * NT1 + NT] = y;
    }

    // drain outstanding DMAs before endpgm
    asm volatile("s_waitcnt vmcnt(0) lgkmcnt(0)");
}

// ---------------------------------------------------------------------------
// Fallback (ws too small): validated round-1 kernel.
// ---------------------------------------------------------------------------
__device__ __forceinline__ void fma4(float4& acc, const float4 w, const float s) {
    acc.x = fmaf(w.x, s, acc.x);
    acc.y = fmaf(w.y, s, acc.y);
    acc.z = fmaf(w.z, s, acc.z);
    acc.w = fmaf(w.w, s, acc.w);
}

__global__ __launch_bounds__(512) void rec_fallback(
    const float* __restrict__ states, const int* __restrict__ actions,
    const float* __restrict__ W_ci, const float* __restrict__ b_ci,
    const float* __restrict__ W_ig, const float* __restrict__ b_ig,
    const float* __restrict__ W_og, const float* __restrict__ b_og,
    const float* __restrict__ W_lin, const float* __restrict__ b_lin,
    float* __restrict__ out)
{
    __shared__ __align__(16) float h_lds[2][NU];
    __shared__ __align__(16) float part[4][2][NU];
    __shared__ float ysum[8][2];
    __shared__ float x_lds[2][NS];
    __shared__ int a_lds[2];

    const int tid = threadIdx.x;
    const int b0 = blockIdx.x * 2;
    const int uq = tid & 127;
    const int kq = tid >> 7;
    const int k0 = kq << 7;

    h_lds[0][tid] = 0.0f;
    h_lds[1][tid] = 0.0f;
    float c0 = 0.0f, c1 = 0.0f;
    const float wlin = W_lin[tid];
    const float big_ = b_ig[tid];
    const float blin = b_lin[0];
    const float bc = b_ci[tid], bo = b_og[tid];
    __syncthreads();

    for (int t = 0; t < NT1; ++t) {
        if (tid < 128) {
            const int bb = tid >> 6, i = tid & 63;
            x_lds[bb][i] = states[((size_t)(b0 + bb) * NT1 + t) * NS + i];
        } else if (tid < 130) {
            const int bb = tid - 128;
            a_lds[bb] = (t < NT) ? actions[(b0 + bb) * NT + t] : -1;
        }

        float4 a0 = make_float4(0.f, 0.f, 0.f, 0.f);
        float4 a1 = make_float4(0.f, 0.f, 0.f, 0.f);
        for (int kk = 0; kk < 128; kk += 4) {
            const int k = k0 + kk;
            const float4 h0v = *(const float4*)&h_lds[0][k];
            const float4 h1v = *(const float4*)&h_lds[1][k];
            const float* wr = W_ig + (size_t)k * NU + (uq << 2);
            const float4 w0 = *(const float4*)(wr);
            const float4 w1 = *(const float4*)(wr + NU);
            const float4 w2 = *(const float4*)(wr + 2 * NU);
            const float4 w3 = *(const float4*)(wr + 3 * NU);
            fma4(a0, w0, h0v.x); fma4(a1, w0, h1v.x);
            fma4(a0, w1, h0v.y); fma4(a1, w1, h1v.y);
            fma4(a0, w2, h0v.z); fma4(a1, w2, h1v.z);
            fma4(a0, w3, h0v.w); fma4(a1, w3, h1v.w);
        }
        *(float4*)&part[kq][0][uq << 2] = a0;
        *(float4*)&part[kq][1][uq << 2] = a1;
        __syncthreads();

        float z0 = big_, z1 = big_;
        #pragma unroll
        for (int q = 0; q < 4; ++q) { z0 += part[q][0][tid]; z1 += part[q][1][tid]; }

        float zc0 = bc, zo0 = bo, zc1 = bc, zo1 = bo;
        for (int i = 0; i < NS; ++i) {
            const float wc = W_ci[(size_t)i * NU + tid];
            const float wo = W_og[(size_t)i * NU + tid];
            const float s0v = x_lds[0][i];
            const float s1v = x_lds[1][i];
            zc0 = fmaf(s0v, wc, zc0); zo0 = fmaf(s0v, wo, zo0);
            zc1 = fmaf(s1v, wc, zc1); zo1 = fmaf(s1v, wo, zo1);
        }
        const int a0i = a_lds[0], a1i = a_lds[1];
        if (a0i >= 0) { zc0 += W_ci[(size_t)(NS + a0i) * NU + tid]; zo0 += W_og[(size_t)(NS + a0i) * NU + tid]; }
        if (a1i >= 0) { zc1 += W_ci[(size_t)(NS + a1i) * NU + tid]; zo1 += W_og[(size_t)(NS + a1i) * NU + tid]; }
        const float ci0 = tanh_fast(zc0), og0 = sigf(zo0);
        const float ci1 = tanh_fast(zc1), og1 = sigf(zo1);

        const float ig0 = sigf(z0), ig1 = sigf(z1);
        c0 = fmaf(ci0, ig0, c0);
        c1 = fmaf(ci1, ig1, c1);
        const float h0 = c0 * og0, h1 = c1 * og1;
        h_lds[0][tid] = h0;
        h_lds[1][tid] = h1;

        float y0 = h0 * wlin, y1 = h1 * wlin;
        #pragma unroll
        for (int off = 32; off > 0; off >>= 1) {
            y0 += __shfl_xor(y0, off);
            y1 += __shfl_xor(y1, off);
        }
        if ((tid & 63) == 0) { ysum[tid >> 6][0] = y0; ysum[tid >> 6][1] = y1; }
        __syncthreads();

        if (tid < 2) {
            float y = blin;
            #pragma unroll
            for (int w = 0; w < 8; ++w) y += ysum[w][tid];
            out[(size_t)(b0 + tid) * NT1 + t] = y;
        }
    }
}

extern "C" void kernel_launch(void* const* d_in, const int* in_sizes, int n_in,
                              void* d_out, int out_size, void* d_ws, size_t ws_size,
                              hipStream_t stream) {
    const float* states = (const float*)d_in[0];
    const int*   actions= (const int*)d_in[1];
    const float* W_ci = (const float*)d_in[2];
    const float* b_ci = (const float*)d_in[3];
    const float* W_ig = (const float*)d_in[4];
    const float* b_ig = (const float*)d_in[5];
    const float* W_og = (const float*)d_in[6];
    const float* b_og = (const float*)d_in[7];
    const float* W_lin= (const float*)d_in[8];
    const float* b_lin= (const float*)d_in[9];
    float* out = (float*)d_out;

    const size_t need = CIOG_BYTES + (size_t)PACK_SHORTS * 2;   // ~135 MB
    if (ws_size >= need) {
        uint32_t* ciog = (uint32_t*)d_ws;
        short* pack = (short*)((char*)d_ws + CIOG_BYTES);

        (void)hipFuncSetAttribute((const void*)rec_dma,
                                  hipFuncAttributeMaxDynamicSharedMemorySize, DYN_LDS);

        pack_kernel<<<dim3(64), dim3(512), 0, stream>>>(W_ig, pack);
        ff_kernel<<<dim3(NBATCH * 17), dim3(512), 0, stream>>>(
            states, actions, W_ci, b_ci, W_og, b_og, ciog);
        rec_dma<<<dim3(NBATCH / NBW), dim3(512), DYN_LDS, stream>>>(
            pack, b_ig, W_lin, b_lin, ciog, out);
    } else {
        rec_fallback<<<dim3(NBATCH / 2), dim3(512), 0, stream>>>(
            states, actions, W_ci, b_ci, W_ig, b_ig, W_og, b_og, W_lin, b_lin, out);
    }
}